// Round 7
// baseline (135.222 us; speedup 1.0000x reference)
//
#include <hip/hip_runtime.h>
#include <cmath>

// MHSA cosine-attention block, MI355X/gfx950.  Round 7.
// K0: one-time prep -> Wb[320][64] bf16 (rows: Q128|K128|V64) + bb[320] fp32.
// K1: QKV projection as MFMA GEMM. Q stored pre-scaled by log2e so k2 can
//     use a bare exp2 (v_exp_f32) instead of mul+exp.
// K2: flash attention v4: K chunk staged in LDS (double-buffered); P-matrix
//     LDS ROUND TRIP ELIMINATED -- exp(S^T) in C-layout is exactly the
//     B-operand of mfma_f32_16x16x16_bf16, so PV consumes it in-register.
// K3: coalesced reduce of numP, fp32 SIMT output projection + residual.

typedef __bf16 bf16x8 __attribute__((ext_vector_type(8)));
typedef __bf16 bf16x4 __attribute__((ext_vector_type(4)));
typedef short short4_t __attribute__((ext_vector_type(4)));
typedef float f4_t __attribute__((ext_vector_type(4)));

#define LQ 4096       // sequence length H*W
#define NH 4          // n*heads
#define KS 8          // key splits

__device__ inline f4_t mfma16(bf16x8 a, bf16x8 b, f4_t c) {
    return __builtin_amdgcn_mfma_f32_16x16x32_bf16(a, b, c, 0, 0, 0);
}

#if __has_builtin(__builtin_amdgcn_mfma_f32_16x16x16_bf16)
#define HAVE_PV16 1
__device__ inline f4_t pv_mfma(bf16x4 a, bf16x4 b, f4_t c) {
    return __builtin_amdgcn_mfma_f32_16x16x16_bf16(a, b, c, 0, 0, 0);
}
#elif __has_builtin(__builtin_amdgcn_mfma_f32_16x16x16bf16_1k)
#define HAVE_PV16 1
__device__ inline f4_t pv_mfma(bf16x4 a, bf16x4 b, f4_t c) {
    return __builtin_amdgcn_mfma_f32_16x16x16bf16_1k(
        __builtin_bit_cast(short4_t, a), __builtin_bit_cast(short4_t, b), c, 0, 0, 0);
}
#else
#define HAVE_PV16 0
#endif

// ---------------------------------------------------------------------------
// Kernel 0: weight prep.  grid 5 x 256 thr; block g -> rows g*64..+63.
// Wb row order: 0-127 = Wq (h*64+k), 128-255 = Wk, 256-319 = Wv (h*32+v).
// ---------------------------------------------------------------------------
__global__ void k0_prep(const float* __restrict__ Wq, const float* __restrict__ bq,
                        const float* __restrict__ Wk, const float* __restrict__ bk,
                        const float* __restrict__ Wv, const float* __restrict__ bv,
                        __bf16* __restrict__ Wb, float* __restrict__ bb) {
    const int tid = threadIdx.x;
    const int row = blockIdx.x * 64 + (tid >> 2);
    const int c0  = (tid & 3) * 16;

    const float* wsrc;
    float bval;
    if (row < 128)      { wsrc = Wq + (size_t)row * 64;         bval = bq[row]; }
    else if (row < 256) { wsrc = Wk + (size_t)(row - 128) * 64; bval = bk[row - 128]; }
    else                { wsrc = Wv + (size_t)(row - 256) * 64; bval = bv[row - 256]; }

#pragma unroll
    for (int j = 0; j < 16; ++j)
        Wb[(size_t)row * 64 + c0 + j] = (__bf16)wsrc[c0 + j];
    if ((tid & 3) == 0) bb[row] = bval;
}

// ---------------------------------------------------------------------------
// Kernel 1: QKV projection + normalize via MFMA.
// grid: dim3(128, 2) = l-tile(32) x n.  block: 256 thr = 4 waves.
// Q rows are scaled by log2e so attention can use exp2 directly.
// ---------------------------------------------------------------------------
__global__ __launch_bounds__(256) void k1_qkv(
        const float* __restrict__ x,
        const __bf16* __restrict__ Wb, const float* __restrict__ bb,
        __bf16* __restrict__ Qb, __bf16* __restrict__ Kb,
        __bf16* __restrict__ Vtb) {
    const int tid  = threadIdx.x;
    const int lane = tid & 63;
    const int w    = tid >> 6;
    const int quad = lane >> 4;
    const int l15  = lane & 15;
    const int lt   = blockIdx.x;
    const int n    = blockIdx.y;
    const int l0   = lt * 32;

    __shared__ __bf16 xl[32][72];   // [l][c] bf16, pitch 72 (16B-aligned rows)

    // stage x tile (transpose to [l][c]): coalesced 128B global segments
    {
        const int c0 = tid >> 5, l = tid & 31;
#pragma unroll
        for (int i = 0; i < 8; ++i) {
            const int c = c0 + i * 8;
            xl[l][c] = (__bf16)x[((size_t)n * 64 + c) * LQ + l0 + l];
        }
    }

    // A fragments: Q/K rows w*64 + t*16 + l15, and V rows 256 + w*16 + l15
    bf16x8 af[4][2], av[2];
#pragma unroll
    for (int t = 0; t < 4; ++t)
#pragma unroll
        for (int kh = 0; kh < 2; ++kh)
            af[t][kh] = *(const bf16x8*)(Wb +
                (size_t)(w * 64 + t * 16 + l15) * 64 + kh * 32 + quad * 8);
#pragma unroll
    for (int kh = 0; kh < 2; ++kh)
        av[kh] = *(const bf16x8*)(Wb +
            (size_t)(256 + w * 16 + l15) * 64 + kh * 32 + quad * 8);

    // bias -> accumulator init values (per-lane rows quad*4+r)
    f4_t binit[4], bvinit;
#pragma unroll
    for (int t = 0; t < 4; ++t)
#pragma unroll
        for (int r = 0; r < 4; ++r)
            binit[t][r] = bb[w * 64 + t * 16 + quad * 4 + r];
#pragma unroll
    for (int r = 0; r < 4; ++r)
        bvinit[r] = bb[256 + w * 16 + quad * 4 + r];

    __syncthreads();

    // B fragments from LDS and the 20 MFMAs
    f4_t acc[4][2], vacc[2];
#pragma unroll
    for (int lsub = 0; lsub < 2; ++lsub) {
        bf16x8 bf0 = *(const bf16x8*)&xl[lsub * 16 + l15][quad * 8];
        bf16x8 bf1 = *(const bf16x8*)&xl[lsub * 16 + l15][32 + quad * 8];
#pragma unroll
        for (int t = 0; t < 4; ++t) {
            f4_t a = mfma16(af[t][0], bf0, binit[t]);
            acc[t][lsub] = mfma16(af[t][1], bf1, a);
        }
        f4_t va = mfma16(av[0], bf0, bvinit);
        vacc[lsub] = mfma16(av[1], bf1, va);
    }

    // epilogue: Q/K normalize + k8-tiled store.  Q gets the log2e factor.
    const int nh = n * 2 + (w & 1);
    __bf16* dst  = (w < 2) ? Qb : Kb;
    const float post = (w < 2) ? 1.44269504f : 1.0f;
#pragma unroll
    for (int lsub = 0; lsub < 2; ++lsub) {
        float ss = 0.f;
#pragma unroll
        for (int t = 0; t < 4; ++t)
#pragma unroll
            for (int r = 0; r < 4; ++r)
                ss = fmaf(acc[t][lsub][r], acc[t][lsub][r], ss);
        ss += __shfl_xor(ss, 16, 64);
        ss += __shfl_xor(ss, 32, 64);
        const float rn = post / fmaxf(sqrtf(ss), 1e-6f);

        const int l = l0 + lsub * 16 + l15;
#pragma unroll
        for (int t = 0; t < 4; ++t) {
            bf16x4 pk;
#pragma unroll
            for (int r = 0; r < 4; ++r) pk[r] = (__bf16)(acc[t][lsub][r] * rn);
            const int kc = t * 2 + (quad >> 1);
            *(bf16x4*)(dst + ((size_t)(nh * 8 + kc) * LQ + l) * 8 + (quad & 1) * 4) = pk;
        }
        // V rows: vrow = w*16 + quad*4 + r  (n-local channel h*32+v)
#pragma unroll
        for (int r = 0; r < 4; ++r) {
            const int vrow = w * 16 + quad * 4 + r;
            Vtb[(size_t)(n * 64 + vrow) * LQ + l] = (__bf16)vacc[lsub][r];
        }
    }
}

// ---------------------------------------------------------------------------
// Kernel 2: flash attention v4 (scores bounded, no max tracking).
// grid: (32 q-blocks of 128, nh=4, ks=8) = 1024 blocks x 4 waves.
// K chunk staged in LDS (double-buffered, shuffled layout). PV consumes
// exp(S^T) directly as the B-operand of mfma 16x16x16 -- no LDS round trip.
// ---------------------------------------------------------------------------
__global__ __launch_bounds__(256, 4) void k2_attn(
        const __bf16* __restrict__ Qb, const __bf16* __restrict__ Kb,
        const __bf16* __restrict__ Vtb,
        float* __restrict__ numP, float* __restrict__ denP) {
    const int tid  = threadIdx.x;
    const int lane = tid & 63;
    const int wave = tid >> 6;
    const int quad = lane >> 4;
    const int l15  = lane & 15;
    const int nh   = blockIdx.y;
    const int ks   = blockIdx.z;
    const int qbase = blockIdx.x * 128 + wave * 32;
    const int kbase = ks * 512;

    __shared__ __bf16 Kl[2][2048];       // 2 x 4 KB staged K chunks
#if !HAVE_PV16
    __shared__ __bf16 P[4][2][16][40];
#endif

    const f4_t fzero = {0.f, 0.f, 0.f, 0.f};

    // staging slot -> source (kc, l) for this thread (constant per thread)
    const int s_kc = ((tid >> 6) & 1) * 4 + ((tid >> 4) & 3);
    const int s_l  = ((tid >> 7) << 4) | (tid & 15);
    const __bf16* s_src = Kb + ((size_t)(nh * 8 + s_kc) * LQ + kbase + s_l) * 8;

    // Q fragments (k8-tiled layout), reused for all 512 keys
    bf16x8 qf[2][2];
#pragma unroll
    for (int qt = 0; qt < 2; ++qt)
#pragma unroll
        for (int kh = 0; kh < 2; ++kh)
            qf[qt][kh] = *(const bf16x8*)(Qb +
                ((size_t)(nh * 8 + kh * 4 + quad) * LQ + qbase + qt * 16 + l15) * 8);

    f4_t racc[2][2];                     // [vt][qt]: R[v=vt*16+quad*4+r][q=qt*16+l15]
#pragma unroll
    for (int a = 0; a < 2; ++a)
#pragma unroll
        for (int b = 0; b < 2; ++b) racc[a][b] = fzero;
    float den[2] = {0.f, 0.f};

    // stage chunk 0 into buffer 0
    *(bf16x8*)&Kl[0][tid * 8] = *(const bf16x8*)s_src;
    __syncthreads();

    for (int ch = 0; ch < 16; ++ch) {
        const int cur = ch & 1;

        // stage next chunk into the other buffer (overlaps this chunk's compute)
        if (ch < 15)
            *(bf16x8*)&Kl[cur ^ 1][tid * 8] =
                *(const bf16x8*)(s_src + (size_t)(ch + 1) * 32 * 8);

        const int kb = kbase + ch * 32;

        // K fragments from staged LDS (contiguous 1 KB per wave-read)
        bf16x8 kf[2][2];
#pragma unroll
        for (int kt = 0; kt < 2; ++kt)
#pragma unroll
            for (int kh = 0; kh < 2; ++kh)
                kf[kt][kh] = *(const bf16x8*)
                    &Kl[cur][(kt * 128 + kh * 64 + quad * 16 + l15) * 8];

        // --- all S^T tiles ---
        f4_t s[2][2];
#pragma unroll
        for (int qt = 0; qt < 2; ++qt)
#pragma unroll
            for (int kt = 0; kt < 2; ++kt) {
                f4_t t = mfma16(kf[kt][0], qf[qt][0], fzero);
                s[qt][kt] = mfma16(kf[kt][1], qf[qt][1], t);
            }

#if HAVE_PV16
        // V A-fragments for K=16 MFMA: A[v=l15][key=quad*4+j]
        bf16x4 vf4[2][2];
#pragma unroll
        for (int vt = 0; vt < 2; ++vt)
#pragma unroll
            for (int kt = 0; kt < 2; ++kt)
                vf4[vt][kt] = *(const bf16x4*)(Vtb +
                    (size_t)(nh * 32 + vt * 16 + l15) * LQ + kb + kt * 16 + quad * 4);

        // --- exp2 + pack; P stays in registers as the PV B-operand ---
        bf16x4 pv[2][2];
#pragma unroll
        for (int qt = 0; qt < 2; ++qt)
#pragma unroll
            for (int kt = 0; kt < 2; ++kt) {
                float d = 0.f;
#pragma unroll
                for (int r = 0; r < 4; ++r) {
                    float p = __builtin_exp2f(s[qt][kt][r]);
                    d += p;
                    pv[qt][kt][r] = (__bf16)p;
                }
                den[qt] += d;
            }

        // --- PV: 8 MFMAs 16x16x16, B = pv in-register ---
#pragma unroll
        for (int qt = 0; qt < 2; ++qt)
#pragma unroll
            for (int kt = 0; kt < 2; ++kt)
#pragma unroll
                for (int vt = 0; vt < 2; ++vt)
                    racc[vt][qt] = pv_mfma(vf4[vt][kt], pv[qt][kt], racc[vt][qt]);
#else
        // fallback: P LDS round trip + K=32 PV
        bf16x8 vf[2];
#pragma unroll
        for (int vt = 0; vt < 2; ++vt)
            vf[vt] = *(const bf16x8*)(Vtb +
                (size_t)(nh * 32 + vt * 16 + l15) * LQ + kb + quad * 8);
#pragma unroll
        for (int qt = 0; qt < 2; ++qt)
#pragma unroll
            for (int kt = 0; kt < 2; ++kt) {
                bf16x4 pvv;
                float d = 0.f;
#pragma unroll
                for (int r = 0; r < 4; ++r) {
                    float p = __builtin_exp2f(s[qt][kt][r]);
                    d += p;
                    pvv[r] = (__bf16)p;
                }
                den[qt] += d;
                *(bf16x4*)&P[wave][qt][l15][kt * 16 + quad * 4] = pvv;
            }
#pragma unroll
        for (int qt = 0; qt < 2; ++qt) {
            bf16x8 pf = *(const bf16x8*)&P[wave][qt][l15][quad * 8];
#pragma unroll
            for (int vt = 0; vt < 2; ++vt)
                racc[vt][qt] = mfma16(vf[vt], pf, racc[vt][qt]);
        }
#endif

        __syncthreads();   // next-buffer staging complete + cur free to overwrite
    }

    // den: reduce quad partials (same q = l15 across quads)
#pragma unroll
    for (int qt = 0; qt < 2; ++qt) {
        den[qt] += __shfl_xor(den[qt], 16, 64);
        den[qt] += __shfl_xor(den[qt], 32, 64);
    }

    const size_t pb = (size_t)(nh * KS + ks) * LQ;
    // numP layout [nh][ks][q][v32] -- v-contiguous for k3's coalesced reads
#pragma unroll
    for (int vt = 0; vt < 2; ++vt)
#pragma unroll
        for (int qt = 0; qt < 2; ++qt)
#pragma unroll
            for (int r = 0; r < 4; ++r)
                numP[(pb + qbase + qt * 16 + l15) * 32 + vt * 16 + quad * 4 + r]
                    = racc[vt][qt][r];

    if (lane < 16)
#pragma unroll
        for (int qt = 0; qt < 2; ++qt)
            denP[pb + qbase + qt * 16 + lane] = den[qt];
}

// ---------------------------------------------------------------------------
// Kernel 3: reduce partials -> R, fp32 SIMT output projection + residual.
// grid: 128 blocks = n(2) x 64 l-tiles of 64.  block: 256 thr = 4 waves.
// ---------------------------------------------------------------------------
__global__ __launch_bounds__(256) void k3_out(
        const float* __restrict__ numP, const float* __restrict__ denP,
        const float* __restrict__ Wm, const float* __restrict__ bm,
        const float* __restrict__ x, float* __restrict__ out) {
    const int tid  = threadIdx.x;
    const int lane = tid & 63;
    const int wv   = tid >> 6;
    const int n    = blockIdx.x >> 6;
    const int lt   = blockIdx.x & 63;
    const int l0   = lt * 64;

    __shared__ float Rf[64][65];    // [j = h*32+v][l], +1 pad
    __shared__ float dinv[2][64];

    if (tid < 128) {
        const int hh = tid >> 6, li = tid & 63;
        float s = 0.f;
#pragma unroll
        for (int k = 0; k < KS; ++k)
            s += denP[(size_t)((n * 2 + hh) * KS + k) * LQ + l0 + li];
        dinv[hh][li] = 1.0f / s;
    }

    // reduce numP over ks: thread (v = tid&31, lsub = tid>>5) owns 2hh x 8l
    {
        const int v = tid & 31, lsub = tid >> 5;
#pragma unroll
        for (int hh = 0; hh < 2; ++hh) {
            const size_t base = (size_t)(n * 2 + hh) * KS * LQ;
#pragma unroll
            for (int i = 0; i < 8; ++i) {
                const int l = lsub + 8 * i;
                float s = 0.f;
#pragma unroll
                for (int k = 0; k < KS; ++k)
                    s += numP[(base + (size_t)k * LQ + l0 + l) * 32 + v];
                Rf[hh * 32 + v][l] = s;
            }
        }
    }
    __syncthreads();

    // projection: wave wv -> outputs o = wv*16..+15, lane = l
    const float d0 = dinv[0][lane], d1 = dinv[1][lane];
    float rj[64];
#pragma unroll
    for (int j = 0; j < 64; ++j)
        rj[j] = Rf[j][lane] * (j < 32 ? d0 : d1);

    float acc[16];
#pragma unroll
    for (int oi = 0; oi < 16; ++oi) acc[oi] = bm[wv * 16 + oi];
#pragma unroll
    for (int oi = 0; oi < 16; ++oi) {
        const float* wr = Wm + (size_t)(wv * 16 + oi) * 64;
        float a = acc[oi];
#pragma unroll
        for (int j4 = 0; j4 < 16; ++j4) {
            f4_t t = *(const f4_t*)(wr + j4 * 4);
            a = fmaf(t[0], rj[j4 * 4 + 0], a);
            a = fmaf(t[1], rj[j4 * 4 + 1], a);
            a = fmaf(t[2], rj[j4 * 4 + 2], a);
            a = fmaf(t[3], rj[j4 * 4 + 3], a);
        }
        acc[oi] = a;
    }

#pragma unroll
    for (int oi = 0; oi < 16; ++oi) {
        const int o = wv * 16 + oi;
        const size_t idx = (size_t)(n * 64 + o) * LQ + l0 + lane;
        out[idx] = acc[oi] + x[idx];
    }
}

// ---------------------------------------------------------------------------
extern "C" void kernel_launch(void* const* d_in, const int* in_sizes, int n_in,
                              void* d_out, int out_size, void* d_ws, size_t ws_size,
                              hipStream_t stream) {
    const float* x  = (const float*)d_in[0];
    const float* Wq = (const float*)d_in[1];
    const float* bq = (const float*)d_in[2];
    const float* Wk = (const float*)d_in[3];
    const float* bk = (const float*)d_in[4];
    const float* Wv = (const float*)d_in[5];
    const float* bv = (const float*)d_in[6];
    const float* Wm = (const float*)d_in[7];
    const float* bm = (const float*)d_in[8];
    float* out = (float*)d_out;

    // workspace carve: Qb 2MB | Kb 2MB | Vtb 1MB | numP 16.8MB | denP 0.5MB | Wb 40KB | bb
    __bf16* Qb  = (__bf16*)d_ws;
    __bf16* Kb  = Qb + (size_t)NH * LQ * 64;
    __bf16* Vtb = Kb + (size_t)NH * LQ * 64;
    float*  numP = (float*)(Vtb + (size_t)NH * 32 * LQ);
    float*  denP = numP + (size_t)NH * KS * 32 * LQ;
    __bf16* Wb  = (__bf16*)(denP + (size_t)NH * KS * LQ);
    float*  bb  = (float*)(Wb + 320 * 64);

    k0_prep<<<dim3(5), dim3(256), 0, stream>>>(Wq, bq, Wk, bk, Wv, bv, Wb, bb);
    k1_qkv<<<dim3(128, 2), dim3(256), 0, stream>>>(x, Wb, bb, Qb, Kb, Vtb);
    k2_attn<<<dim3(32, NH, KS), dim3(256), 0, stream>>>(Qb, Kb, Vtb, numP, denP);
    k3_out<<<dim3(128), dim3(256), 0, stream>>>(numP, denP, Wm, bm, x, out);
}

// Round 8
// 114.690 us; speedup vs baseline: 1.1790x; 1.1790x over previous
//
#include <hip/hip_runtime.h>
#include <cmath>

// MHSA cosine-attention block, MI355X/gfx950.  Round 8.
// K1: QKV projection as MFMA GEMM; A-fragments converted fp32->bf16 in-kernel
//     (k0 eliminated). Q pre-scaled by log2e (k2 uses bare exp2).
// K2: flash attention (R6 core: K chunk double-buffered in LDS, shuffled
//     conflict-free map; P via LDS round trip, K=32 PV) + V REGISTER
//     PING-PONG so V's L2 latency overlaps the chunk barrier.
//     numP partials stored as bf16 (half the traffic).
// K3: 512 blocks (16-l tiles), bf16 partial reduce, fp32 projection+residual.

typedef __bf16 bf16x8 __attribute__((ext_vector_type(8)));
typedef __bf16 bf16x4 __attribute__((ext_vector_type(4)));
typedef float f4_t __attribute__((ext_vector_type(4)));

#define LQ 4096       // sequence length H*W
#define NH 4          // n*heads
#define KS 8          // key splits

__device__ inline f4_t mfma16(bf16x8 a, bf16x8 b, f4_t c) {
    return __builtin_amdgcn_mfma_f32_16x16x32_bf16(a, b, c, 0, 0, 0);
}

__device__ inline bf16x8 cvt8(const float* p) {
    f4_t a = *(const f4_t*)p, b = *(const f4_t*)(p + 4);
    bf16x8 r;
    r[0] = (__bf16)a[0]; r[1] = (__bf16)a[1]; r[2] = (__bf16)a[2]; r[3] = (__bf16)a[3];
    r[4] = (__bf16)b[0]; r[5] = (__bf16)b[1]; r[6] = (__bf16)b[2]; r[7] = (__bf16)b[3];
    return r;
}

// ---------------------------------------------------------------------------
// Kernel 1: QKV projection + normalize via MFMA.
// grid: dim3(128, 2) = l-tile(32) x n.  block: 256 thr = 4 waves.
// wave w<2: Q head w; w in {2,3}: K head w-2.  All waves also do V rows
// w*16..+15.  Q rows scaled by log2e.
// ---------------------------------------------------------------------------
__global__ __launch_bounds__(256) void k1_qkv(
        const float* __restrict__ x,
        const float* __restrict__ Wq, const float* __restrict__ bq,
        const float* __restrict__ Wk, const float* __restrict__ bk,
        const float* __restrict__ Wv, const float* __restrict__ bv,
        __bf16* __restrict__ Qb, __bf16* __restrict__ Kb,
        __bf16* __restrict__ Vtb) {
    const int tid  = threadIdx.x;
    const int lane = tid & 63;
    const int w    = tid >> 6;
    const int quad = lane >> 4;
    const int l15  = lane & 15;
    const int lt   = blockIdx.x;
    const int n    = blockIdx.y;
    const int l0   = lt * 32;

    __shared__ __bf16 xl[32][72];   // [l][c] bf16, pitch 72

    // stage x tile (transpose to [l][c]): coalesced 128B global segments
    {
        const int c0 = tid >> 5, l = tid & 31;
#pragma unroll
        for (int i = 0; i < 8; ++i) {
            const int c = c0 + i * 8;
            xl[l][c] = (__bf16)x[((size_t)n * 64 + c) * LQ + l0 + l];
        }
    }

    const float* Wqk = (w < 2) ? Wq : Wk;
    const float* bqk = (w < 2) ? bq : bk;
    const int h = w & 1;

    // A fragments straight from fp32 weights (cvt in-register)
    bf16x8 af[4][2], av[2];
#pragma unroll
    for (int t = 0; t < 4; ++t)
#pragma unroll
        for (int kh = 0; kh < 2; ++kh)
            af[t][kh] = cvt8(Wqk + (size_t)(h * 64 + t * 16 + l15) * 64
                                  + kh * 32 + quad * 8);
#pragma unroll
    for (int kh = 0; kh < 2; ++kh)
        av[kh] = cvt8(Wv + (size_t)(w * 16 + l15) * 64 + kh * 32 + quad * 8);

    // bias -> accumulator init values (per-lane rows quad*4+r)
    f4_t binit[4], bvinit;
#pragma unroll
    for (int t = 0; t < 4; ++t)
#pragma unroll
        for (int r = 0; r < 4; ++r)
            binit[t][r] = bqk[h * 64 + t * 16 + quad * 4 + r];
#pragma unroll
    for (int r = 0; r < 4; ++r)
        bvinit[r] = bv[w * 16 + quad * 4 + r];

    __syncthreads();

    // B fragments from LDS and the 20 MFMAs
    f4_t acc[4][2], vacc[2];
#pragma unroll
    for (int lsub = 0; lsub < 2; ++lsub) {
        bf16x8 bf0 = *(const bf16x8*)&xl[lsub * 16 + l15][quad * 8];
        bf16x8 bf1 = *(const bf16x8*)&xl[lsub * 16 + l15][32 + quad * 8];
#pragma unroll
        for (int t = 0; t < 4; ++t) {
            f4_t a = mfma16(af[t][0], bf0, binit[t]);
            acc[t][lsub] = mfma16(af[t][1], bf1, a);
        }
        f4_t va = mfma16(av[0], bf0, bvinit);
        vacc[lsub] = mfma16(av[1], bf1, va);
    }

    // epilogue: Q/K normalize + k8-tiled store.  Q gets the log2e factor.
    const int nh = n * 2 + h;
    __bf16* dst  = (w < 2) ? Qb : Kb;
    const float post = (w < 2) ? 1.44269504f : 1.0f;
#pragma unroll
    for (int lsub = 0; lsub < 2; ++lsub) {
        float ss = 0.f;
#pragma unroll
        for (int t = 0; t < 4; ++t)
#pragma unroll
            for (int r = 0; r < 4; ++r)
                ss = fmaf(acc[t][lsub][r], acc[t][lsub][r], ss);
        ss += __shfl_xor(ss, 16, 64);
        ss += __shfl_xor(ss, 32, 64);
        const float rn = post / fmaxf(sqrtf(ss), 1e-6f);

        const int l = l0 + lsub * 16 + l15;
#pragma unroll
        for (int t = 0; t < 4; ++t) {
            bf16x4 pk;
#pragma unroll
            for (int r = 0; r < 4; ++r) pk[r] = (__bf16)(acc[t][lsub][r] * rn);
            const int kc = t * 2 + (quad >> 1);
            *(bf16x4*)(dst + ((size_t)(nh * 8 + kc) * LQ + l) * 8 + (quad & 1) * 4) = pk;
        }
#pragma unroll
        for (int r = 0; r < 4; ++r) {
            const int vrow = w * 16 + quad * 4 + r;
            Vtb[(size_t)(n * 64 + vrow) * LQ + l] = (__bf16)vacc[lsub][r];
        }
    }
}

// ---------------------------------------------------------------------------
// Kernel 2: flash attention (scores bounded, no max tracking).
// grid: (32 q-blocks of 128, nh=4, ks=8) = 1024 blocks x 4 waves.
// K chunk staged in LDS (double-buffered, shuffled conflict-free map).
// V fragments register ping-ponged one chunk ahead (latency overlaps barrier).
// ---------------------------------------------------------------------------
__global__ __launch_bounds__(256, 4) void k2_attn(
        const __bf16* __restrict__ Qb, const __bf16* __restrict__ Kb,
        const __bf16* __restrict__ Vtb,
        __bf16* __restrict__ numPb, float* __restrict__ denP) {
    const int tid  = threadIdx.x;
    const int lane = tid & 63;
    const int wave = tid >> 6;
    const int quad = lane >> 4;
    const int l15  = lane & 15;
    const int nh   = blockIdx.y;
    const int ks   = blockIdx.z;
    const int qbase = blockIdx.x * 128 + wave * 32;
    const int kbase = ks * 512;

    __shared__ __bf16 Kl[2][2048];       // 2 x 4 KB staged K chunks
    __shared__ __bf16 P[4][2][16][40];   // [wave][qt][q-row][32 keys + pad]

    const f4_t fzero = {0.f, 0.f, 0.f, 0.f};

    // staging slot map: slot t <-> (kc = ((t>>6)&1)*4 + ((t>>4)&3),
    //                              l  = ((t>>7)<<4)  | (t&15))
    const int s_kc = ((tid >> 6) & 1) * 4 + ((tid >> 4) & 3);
    const int s_l  = ((tid >> 7) << 4) | (tid & 15);
    const __bf16* s_src = Kb + ((size_t)(nh * 8 + s_kc) * LQ + kbase + s_l) * 8;

    // Q fragments (k8-tiled layout), reused for all 512 keys
    bf16x8 qf[2][2];
#pragma unroll
    for (int qt = 0; qt < 2; ++qt)
#pragma unroll
        for (int kh = 0; kh < 2; ++kh)
            qf[qt][kh] = *(const bf16x8*)(Qb +
                ((size_t)(nh * 8 + kh * 4 + quad) * LQ + qbase + qt * 16 + l15) * 8);

    f4_t racc[2][2];                     // [vt][qt]
#pragma unroll
    for (int a = 0; a < 2; ++a)
#pragma unroll
        for (int b = 0; b < 2; ++b) racc[a][b] = fzero;
    float den[2] = {0.f, 0.f};

    // V source base (vt=0; vt=1 adds 16*LQ); chunk ch adds ch*32
    const __bf16* v_src = Vtb + (size_t)(nh * 32 + l15) * LQ + kbase + quad * 8;
    bf16x8 vf_cur0 = *(const bf16x8*)v_src;
    bf16x8 vf_cur1 = *(const bf16x8*)(v_src + (size_t)16 * LQ);

    // stage chunk 0 into buffer 0
    *(bf16x8*)&Kl[0][tid * 8] = *(const bf16x8*)s_src;
    __syncthreads();

#pragma unroll 2
    for (int ch = 0; ch < 16; ++ch) {
        const int cur = ch & 1;

        // prefetch next chunk: K -> LDS (other buffer), V -> registers
        bf16x8 vf_nxt0, vf_nxt1;
        if (ch < 15) {
            *(bf16x8*)&Kl[cur ^ 1][tid * 8] =
                *(const bf16x8*)(s_src + (size_t)(ch + 1) * 256);
            vf_nxt0 = *(const bf16x8*)(v_src + (ch + 1) * 32);
            vf_nxt1 = *(const bf16x8*)(v_src + (size_t)16 * LQ + (ch + 1) * 32);
        }

        // K fragments from staged LDS (contiguous 1 KB per wave-read)
        bf16x8 kf[2][2];
#pragma unroll
        for (int kt = 0; kt < 2; ++kt)
#pragma unroll
            for (int kh = 0; kh < 2; ++kh)
                kf[kt][kh] = *(const bf16x8*)
                    &Kl[cur][(kt * 128 + kh * 64 + quad * 16 + l15) * 8];

        // --- all S^T tiles ---
        f4_t s[2][2];
#pragma unroll
        for (int qt = 0; qt < 2; ++qt)
#pragma unroll
            for (int kt = 0; kt < 2; ++kt) {
                f4_t t = mfma16(kf[kt][0], qf[qt][0], fzero);
                s[qt][kt] = mfma16(kf[kt][1], qf[qt][1], t);
            }

        // --- exp2 + pack + den + P writes (b64, packed) ---
#pragma unroll
        for (int qt = 0; qt < 2; ++qt)
#pragma unroll
            for (int kt = 0; kt < 2; ++kt) {
                bf16x4 pv;
                float d = 0.f;
#pragma unroll
                for (int r = 0; r < 4; ++r) {
                    float p = __builtin_exp2f(s[qt][kt][r]);
                    d += p;
                    pv[r] = (__bf16)p;
                }
                den[qt] += d;
                *(bf16x4*)&P[wave][qt][l15][kt * 16 + quad * 4] = pv;
            }

        // --- PV: A = V^T rows, B = P rows (same-wave LDS, in-order DS) ---
#pragma unroll
        for (int qt = 0; qt < 2; ++qt) {
            bf16x8 pf = *(const bf16x8*)&P[wave][qt][l15][quad * 8];
            racc[0][qt] = mfma16(vf_cur0, pf, racc[0][qt]);
            racc[1][qt] = mfma16(vf_cur1, pf, racc[1][qt]);
        }

        __syncthreads();   // next-buffer K staged; cur free to overwrite
        vf_cur0 = vf_nxt0;
        vf_cur1 = vf_nxt1;
    }

    // den: reduce quad partials (same q = l15 across quads)
#pragma unroll
    for (int qt = 0; qt < 2; ++qt) {
        den[qt] += __shfl_xor(den[qt], 16, 64);
        den[qt] += __shfl_xor(den[qt], 32, 64);
    }

    const size_t pb = (size_t)(nh * KS + ks) * LQ;
    // numPb layout [nh][ks][q][v32] bf16 -- v-contiguous for k3
#pragma unroll
    for (int vt = 0; vt < 2; ++vt)
#pragma unroll
        for (int qt = 0; qt < 2; ++qt) {
            bf16x4 pk;
#pragma unroll
            for (int r = 0; r < 4; ++r) pk[r] = (__bf16)racc[vt][qt][r];
            *(bf16x4*)(numPb + (pb + qbase + qt * 16 + l15) * 32
                             + vt * 16 + quad * 4) = pk;
        }

    if (lane < 16)
#pragma unroll
        for (int qt = 0; qt < 2; ++qt)
            denP[pb + qbase + qt * 16 + lane] = den[qt];
}

// ---------------------------------------------------------------------------
// Kernel 3: reduce bf16 partials -> R, fp32 projection + bias + residual.
// grid: dim3(256, 2) = l-tile(16) x n = 512 blocks.  block: 256 thr.
// ---------------------------------------------------------------------------
__global__ __launch_bounds__(256) void k3_out(
        const __bf16* __restrict__ numPb, const float* __restrict__ denP,
        const float* __restrict__ Wm, const float* __restrict__ bm,
        const float* __restrict__ x, float* __restrict__ out) {
    const int tid = threadIdx.x;
    const int lt  = blockIdx.x;
    const int n   = blockIdx.y;
    const int l0  = lt * 16;

    __shared__ float Rf[64][17];    // [j = h*32+v][l], pitch 17 (conflict-free)
    __shared__ float dinv[2][16];

    if (tid < 32) {
        const int hh = tid >> 4, li = tid & 15;
        float s = 0.f;
#pragma unroll
        for (int k = 0; k < KS; ++k)
            s += denP[(size_t)((n * 2 + hh) * KS + k) * LQ + l0 + li];
        dinv[hh][li] = 1.0f / s;
    }

    // reduce numPb over ks: group lg = tid>>5 -> (hh = lg&1, lofs = lg>>1)
    {
        const int v = tid & 31, lg = tid >> 5;
        const int hh = lg & 1, lofs = lg >> 1;
        const size_t base = (size_t)(n * 2 + hh) * KS * LQ;
#pragma unroll
        for (int i = 0; i < 4; ++i) {
            const int l = lofs + 4 * i;
            float s = 0.f;
#pragma unroll
            for (int k = 0; k < KS; ++k)
                s += (float)numPb[(base + (size_t)k * LQ + l0 + l) * 32 + v];
            Rf[hh * 32 + v][l] = s;
        }
    }
    __syncthreads();

    // projection: thread (l = tid&15, og = tid>>4) -> outputs og*4..+3
    const int l = tid & 15, og = tid >> 4;
    const float d0 = dinv[0][l], d1 = dinv[1][l];
    float rj[64];
#pragma unroll
    for (int j = 0; j < 64; ++j)
        rj[j] = Rf[j][l] * (j < 32 ? d0 : d1);

#pragma unroll
    for (int oi = 0; oi < 4; ++oi) {
        const int o = og * 4 + oi;
        const float* wr = Wm + (size_t)o * 64;
        float a = bm[o];
#pragma unroll
        for (int j4 = 0; j4 < 16; ++j4) {
            f4_t t = *(const f4_t*)(wr + j4 * 4);
            a = fmaf(t[0], rj[j4 * 4 + 0], a);
            a = fmaf(t[1], rj[j4 * 4 + 1], a);
            a = fmaf(t[2], rj[j4 * 4 + 2], a);
            a = fmaf(t[3], rj[j4 * 4 + 3], a);
        }
        const size_t idx = (size_t)(n * 64 + o) * LQ + l0 + l;
        out[idx] = a + x[idx];
    }
}

// ---------------------------------------------------------------------------
extern "C" void kernel_launch(void* const* d_in, const int* in_sizes, int n_in,
                              void* d_out, int out_size, void* d_ws, size_t ws_size,
                              hipStream_t stream) {
    const float* x  = (const float*)d_in[0];
    const float* Wq = (const float*)d_in[1];
    const float* bq = (const float*)d_in[2];
    const float* Wk = (const float*)d_in[3];
    const float* bk = (const float*)d_in[4];
    const float* Wv = (const float*)d_in[5];
    const float* bv = (const float*)d_in[6];
    const float* Wm = (const float*)d_in[7];
    const float* bm = (const float*)d_in[8];
    float* out = (float*)d_out;

    // workspace carve: Qb 2MB | Kb 2MB | Vtb 1MB | numPb 8.4MB | denP 0.5MB
    __bf16* Qb    = (__bf16*)d_ws;
    __bf16* Kb    = Qb + (size_t)NH * LQ * 64;
    __bf16* Vtb   = Kb + (size_t)NH * LQ * 64;
    __bf16* numPb = Vtb + (size_t)NH * 32 * LQ;
    float*  denP  = (float*)(numPb + (size_t)NH * KS * LQ * 32);

    k1_qkv<<<dim3(128, 2), dim3(256), 0, stream>>>(x, Wq, bq, Wk, bk, Wv, bv,
                                                   Qb, Kb, Vtb);
    k2_attn<<<dim3(32, NH, KS), dim3(256), 0, stream>>>(Qb, Kb, Vtb, numPb, denP);
    k3_out<<<dim3(256, 2), dim3(256), 0, stream>>>(numPb, denP, Wm, bm, x, out);
}

// Round 9
// 112.579 us; speedup vs baseline: 1.2011x; 1.0188x over previous
//
#include <hip/hip_runtime.h>
#include <cmath>

// MHSA cosine-attention block, MI355X/gfx950.  Round 9.
// K1: QKV projection as MFMA GEMM (R8). Q pre-scaled by log2e.
// K2: flash attention v5: 8 chunks x 64 keys (was 16x32) -> HALF the
//     barriers, 2x ILP per stage. K chunk (8 KB) double-buffered in LDS,
//     shuffled conflict-free slot map; K-frags consumed in 2 pairs to bound
//     live VGPRs under the (256,4) cap. V loads issued at chunk start
//     (overlap S-MFMAs). P via same-wave LDS round trip (no barrier).
//     bf16 numP partials.
// K3: 512 blocks (16-l tiles), bf16 partial reduce, fp32 projection+residual.

typedef __bf16 bf16x8 __attribute__((ext_vector_type(8)));
typedef __bf16 bf16x4 __attribute__((ext_vector_type(4)));
typedef float f4_t __attribute__((ext_vector_type(4)));

#define LQ 4096       // sequence length H*W
#define NH 4          // n*heads
#define KS 8          // key splits

__device__ inline f4_t mfma16(bf16x8 a, bf16x8 b, f4_t c) {
    return __builtin_amdgcn_mfma_f32_16x16x32_bf16(a, b, c, 0, 0, 0);
}

__device__ inline bf16x8 cvt8(const float* p) {
    f4_t a = *(const f4_t*)p, b = *(const f4_t*)(p + 4);
    bf16x8 r;
    r[0] = (__bf16)a[0]; r[1] = (__bf16)a[1]; r[2] = (__bf16)a[2]; r[3] = (__bf16)a[3];
    r[4] = (__bf16)b[0]; r[5] = (__bf16)b[1]; r[6] = (__bf16)b[2]; r[7] = (__bf16)b[3];
    return r;
}

// ---------------------------------------------------------------------------
// Kernel 1: QKV projection + normalize via MFMA.  (unchanged from R8)
// grid: dim3(128, 2) = l-tile(32) x n.  block: 256 thr = 4 waves.
// ---------------------------------------------------------------------------
__global__ __launch_bounds__(256) void k1_qkv(
        const float* __restrict__ x,
        const float* __restrict__ Wq, const float* __restrict__ bq,
        const float* __restrict__ Wk, const float* __restrict__ bk,
        const float* __restrict__ Wv, const float* __restrict__ bv,
        __bf16* __restrict__ Qb, __bf16* __restrict__ Kb,
        __bf16* __restrict__ Vtb) {
    const int tid  = threadIdx.x;
    const int lane = tid & 63;
    const int w    = tid >> 6;
    const int quad = lane >> 4;
    const int l15  = lane & 15;
    const int lt   = blockIdx.x;
    const int n    = blockIdx.y;
    const int l0   = lt * 32;

    __shared__ __bf16 xl[32][72];   // [l][c] bf16, pitch 72

    {
        const int c0 = tid >> 5, l = tid & 31;
#pragma unroll
        for (int i = 0; i < 8; ++i) {
            const int c = c0 + i * 8;
            xl[l][c] = (__bf16)x[((size_t)n * 64 + c) * LQ + l0 + l];
        }
    }

    const float* Wqk = (w < 2) ? Wq : Wk;
    const float* bqk = (w < 2) ? bq : bk;
    const int h = w & 1;

    bf16x8 af[4][2], av[2];
#pragma unroll
    for (int t = 0; t < 4; ++t)
#pragma unroll
        for (int kh = 0; kh < 2; ++kh)
            af[t][kh] = cvt8(Wqk + (size_t)(h * 64 + t * 16 + l15) * 64
                                  + kh * 32 + quad * 8);
#pragma unroll
    for (int kh = 0; kh < 2; ++kh)
        av[kh] = cvt8(Wv + (size_t)(w * 16 + l15) * 64 + kh * 32 + quad * 8);

    f4_t binit[4], bvinit;
#pragma unroll
    for (int t = 0; t < 4; ++t)
#pragma unroll
        for (int r = 0; r < 4; ++r)
            binit[t][r] = bqk[h * 64 + t * 16 + quad * 4 + r];
#pragma unroll
    for (int r = 0; r < 4; ++r)
        bvinit[r] = bv[w * 16 + quad * 4 + r];

    __syncthreads();

    f4_t acc[4][2], vacc[2];
#pragma unroll
    for (int lsub = 0; lsub < 2; ++lsub) {
        bf16x8 bf0 = *(const bf16x8*)&xl[lsub * 16 + l15][quad * 8];
        bf16x8 bf1 = *(const bf16x8*)&xl[lsub * 16 + l15][32 + quad * 8];
#pragma unroll
        for (int t = 0; t < 4; ++t) {
            f4_t a = mfma16(af[t][0], bf0, binit[t]);
            acc[t][lsub] = mfma16(af[t][1], bf1, a);
        }
        f4_t va = mfma16(av[0], bf0, bvinit);
        vacc[lsub] = mfma16(av[1], bf1, va);
    }

    const int nh = n * 2 + h;
    __bf16* dst  = (w < 2) ? Qb : Kb;
    const float post = (w < 2) ? 1.44269504f : 1.0f;
#pragma unroll
    for (int lsub = 0; lsub < 2; ++lsub) {
        float ss = 0.f;
#pragma unroll
        for (int t = 0; t < 4; ++t)
#pragma unroll
            for (int r = 0; r < 4; ++r)
                ss = fmaf(acc[t][lsub][r], acc[t][lsub][r], ss);
        ss += __shfl_xor(ss, 16, 64);
        ss += __shfl_xor(ss, 32, 64);
        const float rn = post / fmaxf(sqrtf(ss), 1e-6f);

        const int l = l0 + lsub * 16 + l15;
#pragma unroll
        for (int t = 0; t < 4; ++t) {
            bf16x4 pk;
#pragma unroll
            for (int r = 0; r < 4; ++r) pk[r] = (__bf16)(acc[t][lsub][r] * rn);
            const int kc = t * 2 + (quad >> 1);
            *(bf16x4*)(dst + ((size_t)(nh * 8 + kc) * LQ + l) * 8 + (quad & 1) * 4) = pk;
        }
#pragma unroll
        for (int r = 0; r < 4; ++r) {
            const int vrow = w * 16 + quad * 4 + r;
            Vtb[(size_t)(n * 64 + vrow) * LQ + l] = (__bf16)vacc[lsub][r];
        }
    }
}

// ---------------------------------------------------------------------------
// Kernel 2: flash attention v5 (scores bounded, no max tracking).
// grid: (32 q-blocks of 128, nh=4, ks=8) = 1024 blocks x 4 waves.
// 8 chunks x 64 keys; K double-buffered in LDS (shuffled map: slot
// s <-> (kc = ((s>>6)&1)*4 + ((s>>4)&3), l = (s>>7)*16 + (s&15)));
// staging writes and frag reads both contiguous 1 KB/wave.
// ---------------------------------------------------------------------------
__global__ __launch_bounds__(256, 4) void k2_attn(
        const __bf16* __restrict__ Qb, const __bf16* __restrict__ Kb,
        const __bf16* __restrict__ Vtb,
        __bf16* __restrict__ numPb, float* __restrict__ denP) {
    const int tid  = threadIdx.x;
    const int lane = tid & 63;
    const int wave = tid >> 6;
    const int quad = lane >> 4;
    const int l15  = lane & 15;
    const int nh   = blockIdx.y;
    const int ks   = blockIdx.z;
    const int qbase = blockIdx.x * 128 + wave * 32;
    const int kbase = ks * 512;

    __shared__ __bf16 Kl[2][4096];       // 2 x 8 KB staged K chunks (64 keys)
    __shared__ __bf16 P[4][2][16][72];   // [wave][qt][q-row][64 keys + pad]

    const f4_t fzero = {0.f, 0.f, 0.f, 0.f};

    // staging: 2 slots per thread (s = tid, s = tid + 256)
    const __bf16* s_src0, * s_src1;
    {
        const int s0 = tid, s1 = tid + 256;
        const int kc0 = ((s0 >> 6) & 1) * 4 + ((s0 >> 4) & 3);
        const int ll0 = (s0 >> 7) * 16 + (s0 & 15);
        const int kc1 = ((s1 >> 6) & 1) * 4 + ((s1 >> 4) & 3);
        const int ll1 = (s1 >> 7) * 16 + (s1 & 15);
        s_src0 = Kb + ((size_t)(nh * 8 + kc0) * LQ + kbase + ll0) * 8;
        s_src1 = Kb + ((size_t)(nh * 8 + kc1) * LQ + kbase + ll1) * 8;
    }

    // Q fragments (k8-tiled layout), reused for all 512 keys
    bf16x8 qf[2][2];
#pragma unroll
    for (int qt = 0; qt < 2; ++qt)
#pragma unroll
        for (int kh = 0; kh < 2; ++kh)
            qf[qt][kh] = *(const bf16x8*)(Qb +
                ((size_t)(nh * 8 + kh * 4 + quad) * LQ + qbase + qt * 16 + l15) * 8);

    f4_t racc[2][2];                     // [vt][qt]
#pragma unroll
    for (int a = 0; a < 2; ++a)
#pragma unroll
        for (int b = 0; b < 2; ++b) racc[a][b] = fzero;
    float den[2] = {0.f, 0.f};

    // V base: lane reads V[v = vt*16+l15][key = kp*32 + quad*8 ..+8]
    const __bf16* v_src = Vtb + (size_t)(nh * 32 + l15) * LQ + kbase + quad * 8;

    // stage chunk 0 into buffer 0
    *(bf16x8*)&Kl[0][(size_t)tid * 8]         = *(const bf16x8*)s_src0;
    *(bf16x8*)&Kl[0][(size_t)(tid + 256) * 8] = *(const bf16x8*)s_src1;
    __syncthreads();

#pragma unroll 2
    for (int ch = 0; ch < 8; ++ch) {
        const int cur = ch & 1;

        // stage next chunk (overlaps this chunk's compute)
        if (ch < 7) {
            *(bf16x8*)&Kl[cur ^ 1][(size_t)tid * 8] =
                *(const bf16x8*)(s_src0 + (size_t)(ch + 1) * 512);
            *(bf16x8*)&Kl[cur ^ 1][(size_t)(tid + 256) * 8] =
                *(const bf16x8*)(s_src1 + (size_t)(ch + 1) * 512);
        }

        // V fragments for THIS chunk (issued early; overlap the S MFMAs)
        bf16x8 vf[2][2];   // [vt][kp]
#pragma unroll
        for (int vt = 0; vt < 2; ++vt)
#pragma unroll
            for (int kp = 0; kp < 2; ++kp)
                vf[vt][kp] = *(const bf16x8*)(v_src + (size_t)vt * 16 * LQ
                                              + ch * 64 + kp * 32);

        // S^T + exp in 2 key-tile pairs (bounds live registers)
#pragma unroll
        for (int ktp = 0; ktp < 2; ++ktp) {
            bf16x8 kf[2][2];
#pragma unroll
            for (int i = 0; i < 2; ++i)
#pragma unroll
                for (int kh = 0; kh < 2; ++kh)
                    kf[i][kh] = *(const bf16x8*)
                        &Kl[cur][(size_t)((ktp * 2 + i) * 128 + kh * 64
                                          + quad * 16 + l15) * 8];

            f4_t s[2][2];
#pragma unroll
            for (int qt = 0; qt < 2; ++qt)
#pragma unroll
                for (int i = 0; i < 2; ++i) {
                    f4_t t = mfma16(kf[i][0], qf[qt][0], fzero);
                    s[qt][i] = mfma16(kf[i][1], qf[qt][1], t);
                }

#pragma unroll
            for (int qt = 0; qt < 2; ++qt)
#pragma unroll
                for (int i = 0; i < 2; ++i) {
                    bf16x4 pv;
                    float d = 0.f;
#pragma unroll
                    for (int r = 0; r < 4; ++r) {
                        float p = __builtin_exp2f(s[qt][i][r]);
                        d += p;
                        pv[r] = (__bf16)p;
                    }
                    den[qt] += d;
                    *(bf16x4*)&P[wave][qt][l15][(ktp * 2 + i) * 16 + quad * 4] = pv;
                }
        }

        // PV: A = V rows, B = P rows (same-wave LDS, in-order DS)
#pragma unroll
        for (int qt = 0; qt < 2; ++qt)
#pragma unroll
            for (int kp = 0; kp < 2; ++kp) {
                bf16x8 pf = *(const bf16x8*)&P[wave][qt][l15][kp * 32 + quad * 8];
                racc[0][qt] = mfma16(vf[0][kp], pf, racc[0][qt]);
                racc[1][qt] = mfma16(vf[1][kp], pf, racc[1][qt]);
            }

        __syncthreads();   // next-buffer K staged; cur free to overwrite
    }

    // den: reduce quad partials (same q = l15 across quads)
#pragma unroll
    for (int qt = 0; qt < 2; ++qt) {
        den[qt] += __shfl_xor(den[qt], 16, 64);
        den[qt] += __shfl_xor(den[qt], 32, 64);
    }

    const size_t pb = (size_t)(nh * KS + ks) * LQ;
    // numPb layout [nh][ks][q][v32] bf16 -- v-contiguous for k3
#pragma unroll
    for (int vt = 0; vt < 2; ++vt)
#pragma unroll
        for (int qt = 0; qt < 2; ++qt) {
            bf16x4 pk;
#pragma unroll
            for (int r = 0; r < 4; ++r) pk[r] = (__bf16)racc[vt][qt][r];
            *(bf16x4*)(numPb + (pb + qbase + qt * 16 + l15) * 32
                             + vt * 16 + quad * 4) = pk;
        }

    if (lane < 16)
#pragma unroll
        for (int qt = 0; qt < 2; ++qt)
            denP[pb + qbase + qt * 16 + lane] = den[qt];
}

// ---------------------------------------------------------------------------
// Kernel 3: reduce bf16 partials -> R, fp32 projection + bias + residual.
// grid: dim3(256, 2) = l-tile(16) x n = 512 blocks.  block: 256 thr.
// ---------------------------------------------------------------------------
__global__ __launch_bounds__(256) void k3_out(
        const __bf16* __restrict__ numPb, const float* __restrict__ denP,
        const float* __restrict__ Wm, const float* __restrict__ bm,
        const float* __restrict__ x, float* __restrict__ out) {
    const int tid = threadIdx.x;
    const int lt  = blockIdx.x;
    const int n   = blockIdx.y;
    const int l0  = lt * 16;

    __shared__ float Rf[64][17];    // [j = h*32+v][l], pitch 17
    __shared__ float dinv[2][16];

    if (tid < 32) {
        const int hh = tid >> 4, li = tid & 15;
        float s = 0.f;
#pragma unroll
        for (int k = 0; k < KS; ++k)
            s += denP[(size_t)((n * 2 + hh) * KS + k) * LQ + l0 + li];
        dinv[hh][li] = 1.0f / s;
    }

    {
        const int v = tid & 31, lg = tid >> 5;
        const int hh = lg & 1, lofs = lg >> 1;
        const size_t base = (size_t)(n * 2 + hh) * KS * LQ;
#pragma unroll
        for (int i = 0; i < 4; ++i) {
            const int l = lofs + 4 * i;
            float s = 0.f;
#pragma unroll
            for (int k = 0; k < KS; ++k)
                s += (float)numPb[(base + (size_t)k * LQ + l0 + l) * 32 + v];
            Rf[hh * 32 + v][l] = s;
        }
    }
    __syncthreads();

    const int l = tid & 15, og = tid >> 4;
    const float d0 = dinv[0][l], d1 = dinv[1][l];
    float rj[64];
#pragma unroll
    for (int j = 0; j < 64; ++j)
        rj[j] = Rf[j][l] * (j < 32 ? d0 : d1);

#pragma unroll
    for (int oi = 0; oi < 4; ++oi) {
        const int o = og * 4 + oi;
        const float* wr = Wm + (size_t)o * 64;
        float a = bm[o];
#pragma unroll
        for (int j4 = 0; j4 < 16; ++j4) {
            f4_t t = *(const f4_t*)(wr + j4 * 4);
            a = fmaf(t[0], rj[j4 * 4 + 0], a);
            a = fmaf(t[1], rj[j4 * 4 + 1], a);
            a = fmaf(t[2], rj[j4 * 4 + 2], a);
            a = fmaf(t[3], rj[j4 * 4 + 3], a);
        }
        const size_t idx = (size_t)(n * 64 + o) * LQ + l0 + l;
        out[idx] = a + x[idx];
    }
}

// ---------------------------------------------------------------------------
extern "C" void kernel_launch(void* const* d_in, const int* in_sizes, int n_in,
                              void* d_out, int out_size, void* d_ws, size_t ws_size,
                              hipStream_t stream) {
    const float* x  = (const float*)d_in[0];
    const float* Wq = (const float*)d_in[1];
    const float* bq = (const float*)d_in[2];
    const float* Wk = (const float*)d_in[3];
    const float* bk = (const float*)d_in[4];
    const float* Wv = (const float*)d_in[5];
    const float* bv = (const float*)d_in[6];
    const float* Wm = (const float*)d_in[7];
    const float* bm = (const float*)d_in[8];
    float* out = (float*)d_out;

    // workspace carve: Qb 2MB | Kb 2MB | Vtb 1MB | numPb 8.4MB | denP 0.5MB
    __bf16* Qb    = (__bf16*)d_ws;
    __bf16* Kb    = Qb + (size_t)NH * LQ * 64;
    __bf16* Vtb   = Kb + (size_t)NH * LQ * 64;
    __bf16* numPb = Vtb + (size_t)NH * 32 * LQ;
    float*  denP  = (float*)(numPb + (size_t)NH * KS * LQ * 32);

    k1_qkv<<<dim3(128, 2), dim3(256), 0, stream>>>(x, Wq, bq, Wk, bk, Wv, bv,
                                                   Qb, Kb, Vtb);
    k2_attn<<<dim3(32, NH, KS), dim3(256), 0, stream>>>(Qb, Kb, Vtb, numPb, denP);
    k3_out<<<dim3(256, 2), dim3(256), 0, stream>>>(numPb, denP, Wm, bm, x, out);
}